// Round 5
// baseline (369.691 us; speedup 1.0000x reference)
//
#include <hip/hip_runtime.h>

#define N_IN 128
#define HID 256
#define NB 16
#define BM 128
#define HS_STRIDE 264   // bf16 row stride for H tile (16B pad -> 2-way banks only, free)
#define BS_STRIDE 17    // basis LDS stride (f32)

typedef __attribute__((ext_vector_type(8))) short s8v;   // 8 bf16 = 4 VGPRs
typedef __attribute__((ext_vector_type(4))) float f4v;   // MFMA 16x16x32 accumulator

__device__ __forceinline__ unsigned short f2bf(float f) {
  unsigned int u = __float_as_uint(f);
  u += 0x7fffu + ((u >> 16) & 1u);   // round-to-nearest-even
  return (unsigned short)(u >> 16);
}

__device__ __forceinline__ float tanh_fast(float x) {
  float e = __expf(2.0f * x);
  return 1.0f - 2.0f * __builtin_amdgcn_rcpf(e + 1.0f);
}

// Fragment-ordered bf16 repack (1 KB coalesced MFMA fragments).
// W1f frag (pass,kk,ct): n = pass*128+ct*16+l15, k = kk*32+quad*8+j, val = W1[k*256+n]
// W2f frag (b,kk,ct):    n = ct*16+l15,          k = kk*32+quad*8+j, val = W2[k*2048+n*16+b]
__global__ void prep_kernel(const float* __restrict__ W1, const float* __restrict__ W2,
                            unsigned short* __restrict__ W1f, unsigned short* __restrict__ W2f) {
  int tid = blockIdx.x * blockDim.x + threadIdx.x;
  if (tid < N_IN * HID) {
    int j = tid & 7, lane = (tid >> 3) & 63, ct = (tid >> 9) & 7, kk = (tid >> 12) & 3, pass = tid >> 14;
    int n = pass * 128 + ct * 16 + (lane & 15);
    int k = kk * 32 + (lane >> 4) * 8 + j;
    W1f[tid] = f2bf(W1[k * HID + n]);
  }
  int i = tid - N_IN * HID;
  if (i >= 0 && i < HID * (N_IN * NB)) {
    int j = i & 7, lane = (i >> 3) & 63, ct = (i >> 9) & 7, kk = (i >> 12) & 7, b = i >> 15;
    int n = ct * 16 + (lane & 15);
    int k = kk * 32 + (lane >> 4) * 8 + j;
    W2f[i] = f2bf(W2[k * (N_IN * NB) + n * 16 + b]);
  }
}

// ================= Round-5: two-kernel split =================
// h_kernel: gather + W1 MFMA + tanh -> H written to workspace in MFMA-fragment
// order (frag (rowblk,kk): lane l holds row=rowblk*16+(l&15), k=kk*32+(l>>4)*8+j).
// c_kernel: pure GEMM H@W2f with basis contraction; A-frags loaded straight from
// global (coalesced dwordx4), NO Hs LDS, NO phase barrier -> occupancy reg-bound
// (~10 waves/CU vs 8) and waves fully independent.

__global__ void __launch_bounds__(256, 2)
h_kernel(const float* __restrict__ prop,
         const int* __restrict__ idx_i,
         const int* __restrict__ idx_j,
         const unsigned short* __restrict__ W1f,
         unsigned short* __restrict__ Hg, int P) {
  __shared__ unsigned short Hs[BM * HS_STRIDE];   // 67,584 B

  const int t = threadIdx.x;
  const int lane = t & 63;
  const int wv = t >> 6;
  const int l15 = lane & 15;
  const int l4 = lane >> 4;
  const int tile0 = blockIdx.x * BM;
  const int row0 = wv * 32;

  int pidx[2], qidx[2];
#pragma unroll
  for (int rt = 0; rt < 2; ++rt) {
    int p = tile0 + row0 + rt * 16 + l15; if (p >= P) p = P - 1;
    pidx[rt] = idx_i[p];
    qidx[rt] = idx_j[p];
  }

  // ---- phase B verbatim (proven): gathers hoisted, both passes ----
  {
    s8v afr[4][2];   // [kk][rt], 32 VGPR
#pragma unroll
    for (int kk = 0; kk < 4; ++kk) {
      int k0 = kk * 32 + l4 * 8;
#pragma unroll
      for (int rt = 0; rt < 2; ++rt) {
        const float4* ai = (const float4*)(prop + (long)pidx[rt] * N_IN + k0);
        const float4* aj = (const float4*)(prop + (long)qidx[rt] * N_IN + k0);
        float4 x0 = ai[0], x1 = ai[1];
        float4 y0 = aj[0], y1 = aj[1];
        s8v a;
        a[0] = (short)f2bf(x0.x + y0.x); a[1] = (short)f2bf(x0.y + y0.y);
        a[2] = (short)f2bf(x0.z + y0.z); a[3] = (short)f2bf(x0.w + y0.w);
        a[4] = (short)f2bf(x1.x + y1.x); a[5] = (short)f2bf(x1.y + y1.y);
        a[6] = (short)f2bf(x1.z + y1.z); a[7] = (short)f2bf(x1.w + y1.w);
        afr[kk][rt] = a;
      }
    }
#pragma unroll
    for (int pass = 0; pass < 2; ++pass) {
      f4v acc[2][8];
#pragma unroll
      for (int rt = 0; rt < 2; ++rt)
#pragma unroll
        for (int ct = 0; ct < 8; ++ct) acc[rt][ct] = (f4v){0.f, 0.f, 0.f, 0.f};
#pragma unroll
      for (int kk = 0; kk < 4; ++kk) {
#pragma unroll
        for (int ct = 0; ct < 8; ++ct) {
          s8v bfr = *(const s8v*)(W1f + ((((pass * 4 + kk) * 8 + ct) * 64 + lane) << 3));
#pragma unroll
          for (int rt = 0; rt < 2; ++rt)
            acc[rt][ct] = __builtin_amdgcn_mfma_f32_16x16x32_bf16(afr[kk][rt], bfr, acc[rt][ct], 0, 0, 0);
        }
      }
#pragma unroll
      for (int rt = 0; rt < 2; ++rt)
#pragma unroll
        for (int ct = 0; ct < 8; ++ct)
#pragma unroll
          for (int r = 0; r < 4; ++r) {
            int lrow = row0 + rt * 16 + l4 * 4 + r;
            int col = pass * 128 + ct * 16 + l15;
            Hs[lrow * HS_STRIDE + col] = f2bf(tanh_fast(acc[rt][ct][r]));
          }
    }
  }

  __syncthreads();

  // ---- cooperative fragment-order writeout: 64 frags x 64 lanes x 16B = 64 KB.
  // nt stores: H is 102 MB (never L2-resident), read exactly once by c_kernel. ----
  {
    const int fbase = t >> 6;          // 0..3
    unsigned short* base = Hg + ((long)blockIdx.x << 15);   // 64 frags * 512 shorts
#pragma unroll
    for (int fi = 0; fi < 16; ++fi) {
      int frag = fi * 4 + fbase;       // 0..63
      int rowblk = frag >> 3, kk = frag & 7;
      int row = rowblk * 16 + l15;
      int k0 = kk * 32 + l4 * 8;
      s8v v = *(const s8v*)&Hs[row * HS_STRIDE + k0];
      __builtin_nontemporal_store(v, (s8v*)(base + ((frag * 64 + lane) << 3)));
    }
  }
}

__global__ void __launch_bounds__(256, 2)
c_kernel(const unsigned short* __restrict__ Hg,
         const float* __restrict__ basis,
         const unsigned short* __restrict__ W2f,
         float* __restrict__ out, int P) {
  __shared__ float basisS[BM * BS_STRIDE];        // 8,704 B only

  const int t = threadIdx.x;
  const int lane = t & 63;
  const int wv = t >> 6;
  const int l15 = lane & 15;
  const int l4 = lane >> 4;
  const int tile0 = blockIdx.x * BM;

  // ---- stage basis tile cooperatively (nt loads: streamed exactly once) ----
  {
    int r = t >> 1;
    int c0 = (t & 1) * 8;
    int p = tile0 + r; if (p >= P) p = P - 1;
    const f4v* bp = (const f4v*)(basis + (long)p * NB + c0);
    f4v b0 = __builtin_nontemporal_load(bp);
    f4v b1 = __builtin_nontemporal_load(bp + 1);
    float* dst = &basisS[r * BS_STRIDE + c0];
    dst[0] = b0[0]; dst[1] = b0[1]; dst[2] = b0[2]; dst[3] = b0[3];
    dst[4] = b1[0]; dst[5] = b1[1]; dst[6] = b1[2]; dst[7] = b1[3];
  }

  const int rg = wv >> 1, cg = wv & 1;
  const int rbase = rg * 64;

  __syncthreads();   // basisS visible (only barrier in this kernel)

  f4v o[4][4];   // [rt][q] -> rows rbase+rt*16.., cols (cg*4+q)*16..
#pragma unroll
  for (int rt = 0; rt < 4; ++rt)
#pragma unroll
    for (int q = 0; q < 4; ++q) o[rt][q] = (f4v){0.f, 0.f, 0.f, 0.f};

  const unsigned short* hbase = Hg + ((long)blockIdx.x << 15);

#pragma unroll 1
  for (int khalf = 0; khalf < 2; ++khalf) {
    // A-cache: 16 fragments (64 VGPR) straight from global, coalesced dwordx4.
    s8v areg[4][4];   // [rt][kloc]
#pragma unroll
    for (int rt = 0; rt < 4; ++rt)
#pragma unroll
      for (int kloc = 0; kloc < 4; ++kloc) {
        int frag = ((rg * 4 + rt) << 3) + khalf * 4 + kloc;
        areg[rt][kloc] = *(const s8v*)(hbase + ((frag * 64 + lane) << 3));
      }

    s8v bf[4][4];   // register ring of B fragments [slot][kloc], slot = it & 3
    // preload iterations 0,1,2  (b=0, q=0..2)
#pragma unroll
    for (int q0 = 0; q0 < 3; ++q0)
#pragma unroll
      for (int kloc = 0; kloc < 4; ++kloc)
        bf[q0][kloc] = *(const s8v*)(W2f +
            ((((khalf * 4 + kloc) * 8) + cg * 4 + q0) << 9) + lane * 8);

#pragma unroll 1
    for (int b = 0; b < 16; ++b) {
      float bs[4][4];
#pragma unroll
      for (int rt = 0; rt < 4; ++rt)
#pragma unroll
        for (int r = 0; r < 4; ++r)
          bs[rt][r] = basisS[(rbase + rt * 16 + l4 * 4 + r) * BS_STRIDE + b];

#pragma unroll
      for (int q = 0; q < 4; ++q) {
        // prefetch iteration it+3 into slot (q+3)&3  (it = b*4+q)
        {
          int nb = b + ((q + 3) >> 2); if (nb > 15) nb = 15;   // tail: harmless re-read
          int nq = (q + 3) & 3;
#pragma unroll
          for (int kloc = 0; kloc < 4; ++kloc)
            bf[(q + 3) & 3][kloc] = *(const s8v*)(W2f +
                (((nb * 8 + khalf * 4 + kloc) * 8 + cg * 4 + nq) << 9) + lane * 8);
        }
        f4v g[4];
#pragma unroll
        for (int rt = 0; rt < 4; ++rt) g[rt] = (f4v){0.f, 0.f, 0.f, 0.f};
        __builtin_amdgcn_s_setprio(1);   // T5: barrier-free independent waves
#pragma unroll
        for (int kloc = 0; kloc < 4; ++kloc)
#pragma unroll
          for (int rt = 0; rt < 4; ++rt)
            g[rt] = __builtin_amdgcn_mfma_f32_16x16x32_bf16(areg[rt][kloc], bf[q][kloc], g[rt], 0, 0, 0);
        __builtin_amdgcn_s_setprio(0);
#pragma unroll
        for (int rt = 0; rt < 4; ++rt)
#pragma unroll
          for (int r = 0; r < 4; ++r)
            o[rt][q][r] += g[rt][r] * bs[rt][r];
      }
    }
  }

  // ---- epilogue: nt stores (write-once; keep W2f L2-resident) ----
#pragma unroll
  for (int rt = 0; rt < 4; ++rt)
#pragma unroll
    for (int r = 0; r < 4; ++r) {
      int p = tile0 + rbase + rt * 16 + l4 * 4 + r;
      if (p < P) {
        float* op = out + (long)p * N_IN + cg * 64 + l15;
#pragma unroll
        for (int q = 0; q < 4; ++q)
          __builtin_nontemporal_store(o[rt][q][r], op + q * 16);
      }
    }
}

// ================= Fallback: proven round-1 fused kernel (253 us) =================
__global__ void __launch_bounds__(256, 2)
pilayer_kernel(const float* __restrict__ prop,
               const int* __restrict__ idx_i,
               const int* __restrict__ idx_j,
               const float* __restrict__ basis,
               const unsigned short* __restrict__ W1f,
               const unsigned short* __restrict__ W2f,
               float* __restrict__ out, int P) {
  __shared__ unsigned short Hs[BM * HS_STRIDE];
  __shared__ float basisS[BM * BS_STRIDE];

  const int t = threadIdx.x;
  const int lane = t & 63;
  const int wv = t >> 6;
  const int l15 = lane & 15;
  const int l4 = lane >> 4;
  const int tile0 = blockIdx.x * BM;
  const int row0 = wv * 32;

  int pidx[2], qidx[2];
#pragma unroll
  for (int rt = 0; rt < 2; ++rt) {
    int p = tile0 + row0 + rt * 16 + l15; if (p >= P) p = P - 1;
    pidx[rt] = idx_i[p];
    qidx[rt] = idx_j[p];
  }

  {
    int r = t >> 1;
    int c0 = (t & 1) * 8;
    int p = tile0 + r; if (p >= P) p = P - 1;
    const f4v* bp = (const f4v*)(basis + (long)p * NB + c0);
    f4v b0 = __builtin_nontemporal_load(bp);
    f4v b1 = __builtin_nontemporal_load(bp + 1);
    float* dst = &basisS[r * BS_STRIDE + c0];
    dst[0] = b0[0]; dst[1] = b0[1]; dst[2] = b0[2]; dst[3] = b0[3];
    dst[4] = b1[0]; dst[5] = b1[1]; dst[6] = b1[2]; dst[7] = b1[3];
  }

  {
    s8v afr[4][2];
#pragma unroll
    for (int kk = 0; kk < 4; ++kk) {
      int k0 = kk * 32 + l4 * 8;
#pragma unroll
      for (int rt = 0; rt < 2; ++rt) {
        const float4* ai = (const float4*)(prop + (long)pidx[rt] * N_IN + k0);
        const float4* aj = (const float4*)(prop + (long)qidx[rt] * N_IN + k0);
        float4 x0 = ai[0], x1 = ai[1];
        float4 y0 = aj[0], y1 = aj[1];
        s8v a;
        a[0] = (short)f2bf(x0.x + y0.x); a[1] = (short)f2bf(x0.y + y0.y);
        a[2] = (short)f2bf(x0.z + y0.z); a[3] = (short)f2bf(x0.w + y0.w);
        a[4] = (short)f2bf(x1.x + y1.x); a[5] = (short)f2bf(x1.y + y1.y);
        a[6] = (short)f2bf(x1.z + y1.z); a[7] = (short)f2bf(x1.w + y1.w);
        afr[kk][rt] = a;
      }
    }
#pragma unroll
    for (int pass = 0; pass < 2; ++pass) {
      f4v acc[2][8];
#pragma unroll
      for (int rt = 0; rt < 2; ++rt)
#pragma unroll
        for (int ct = 0; ct < 8; ++ct) acc[rt][ct] = (f4v){0.f, 0.f, 0.f, 0.f};
#pragma unroll
      for (int kk = 0; kk < 4; ++kk) {
#pragma unroll
        for (int ct = 0; ct < 8; ++ct) {
          s8v bfr = *(const s8v*)(W1f + ((((pass * 4 + kk) * 8 + ct) * 64 + lane) << 3));
#pragma unroll
          for (int rt = 0; rt < 2; ++rt)
            acc[rt][ct] = __builtin_amdgcn_mfma_f32_16x16x32_bf16(afr[kk][rt], bfr, acc[rt][ct], 0, 0, 0);
        }
      }
#pragma unroll
      for (int rt = 0; rt < 2; ++rt)
#pragma unroll
        for (int ct = 0; ct < 8; ++ct)
#pragma unroll
          for (int r = 0; r < 4; ++r) {
            int lrow = row0 + rt * 16 + l4 * 4 + r;
            int col = pass * 128 + ct * 16 + l15;
            Hs[lrow * HS_STRIDE + col] = f2bf(tanh_fast(acc[rt][ct][r]));
          }
    }
  }

  __syncthreads();

  const int rg = wv >> 1, cg = wv & 1;
  const int rbase = rg * 64;

  f4v o[4][4];
#pragma unroll
  for (int rt = 0; rt < 4; ++rt)
#pragma unroll
    for (int q = 0; q < 4; ++q) o[rt][q] = (f4v){0.f, 0.f, 0.f, 0.f};

#pragma unroll 1
  for (int khalf = 0; khalf < 2; ++khalf) {
    s8v areg[4][4];
#pragma unroll
    for (int rt = 0; rt < 4; ++rt)
#pragma unroll
      for (int kloc = 0; kloc < 4; ++kloc)
        areg[rt][kloc] = *(const s8v*)&Hs[(rbase + rt * 16 + l15) * HS_STRIDE +
                                          (khalf * 4 + kloc) * 32 + l4 * 8];

    s8v bf[4][4];
#pragma unroll
    for (int q0 = 0; q0 < 3; ++q0)
#pragma unroll
      for (int kloc = 0; kloc < 4; ++kloc)
        bf[q0][kloc] = *(const s8v*)(W2f +
            ((((khalf * 4 + kloc) * 8) + cg * 4 + q0) << 9) + lane * 8);

#pragma unroll 1
    for (int b = 0; b < 16; ++b) {
      float bs[4][4];
#pragma unroll
      for (int rt = 0; rt < 4; ++rt)
#pragma unroll
        for (int r = 0; r < 4; ++r)
          bs[rt][r] = basisS[(rbase + rt * 16 + l4 * 4 + r) * BS_STRIDE + b];

#pragma unroll
      for (int q = 0; q < 4; ++q) {
        {
          int nb = b + ((q + 3) >> 2); if (nb > 15) nb = 15;
          int nq = (q + 3) & 3;
#pragma unroll
          for (int kloc = 0; kloc < 4; ++kloc)
            bf[(q + 3) & 3][kloc] = *(const s8v*)(W2f +
                (((nb * 8 + khalf * 4 + kloc) * 8 + cg * 4 + nq) << 9) + lane * 8);
        }
        f4v g[4];
#pragma unroll
        for (int rt = 0; rt < 4; ++rt) g[rt] = (f4v){0.f, 0.f, 0.f, 0.f};
        __builtin_amdgcn_s_setprio(1);
#pragma unroll
        for (int kloc = 0; kloc < 4; ++kloc)
#pragma unroll
          for (int rt = 0; rt < 4; ++rt)
            g[rt] = __builtin_amdgcn_mfma_f32_16x16x32_bf16(areg[rt][kloc], bf[q][kloc], g[rt], 0, 0, 0);
        __builtin_amdgcn_s_setprio(0);
#pragma unroll
        for (int rt = 0; rt < 4; ++rt)
#pragma unroll
          for (int r = 0; r < 4; ++r)
            o[rt][q][r] += g[rt][r] * bs[rt][r];
      }
    }
  }

#pragma unroll
  for (int rt = 0; rt < 4; ++rt)
#pragma unroll
    for (int r = 0; r < 4; ++r) {
      int p = tile0 + rbase + rt * 16 + l4 * 4 + r;
      if (p < P) {
        float* op = out + (long)p * N_IN + cg * 64 + l15;
#pragma unroll
        for (int q = 0; q < 4; ++q)
          __builtin_nontemporal_store(o[rt][q][r], op + q * 16);
      }
    }
}

extern "C" void kernel_launch(void* const* d_in, const int* in_sizes, int n_in,
                              void* d_out, int out_size, void* d_ws, size_t ws_size,
                              hipStream_t stream) {
  const float* prop  = (const float*)d_in[0];
  const int* idx_i   = (const int*)d_in[1];
  const int* idx_j   = (const int*)d_in[2];
  const float* basis = (const float*)d_in[3];
  const float* W1    = (const float*)d_in[4];
  const float* W2    = (const float*)d_in[5];
  float* out = (float*)d_out;
  int P = in_sizes[1];

  unsigned short* W1f = (unsigned short*)d_ws;                 // 32768 bf16
  unsigned short* W2f = W1f + N_IN * HID;                      // 524288 bf16
  unsigned short* Hg  = W2f + HID * (N_IN * NB);               // ntiles*32768 bf16

  int prep_threads = N_IN * HID + HID * N_IN * NB;             // 557056
  prep_kernel<<<(prep_threads + 255) / 256, 256, 0, stream>>>(W1, W2, W1f, W2f);

  int ntiles = (P + BM - 1) / BM;
  size_t need = (size_t)prep_threads * 2 + (size_t)ntiles * 65536;   // ~103.5 MB

  if (ws_size >= need) {
    h_kernel<<<ntiles, 256, 0, stream>>>(prop, idx_i, idx_j, W1f, Hg, P);
    c_kernel<<<ntiles, 256, 0, stream>>>(Hg, basis, W2f, out, P);
  } else {
    pilayer_kernel<<<ntiles, 256, 0, stream>>>(prop, idx_i, idx_j, basis, W1f, W2f, out, P);
  }
}

// Round 9
// 336.565 us; speedup vs baseline: 1.0984x; 1.0984x over previous
//
#include <hip/hip_runtime.h>

#define N_IN 128
#define HID 256
#define NB 16
#define BM 128
#define HS_STRIDE 264   // bf16 row stride for H tile (16B pad -> 2-way banks only, free)
#define BS_STRIDE 17    // basis LDS stride (f32)

typedef __attribute__((ext_vector_type(8))) short s8v;   // 8 bf16 = 4 VGPRs
typedef __attribute__((ext_vector_type(4))) float f4v;   // MFMA 16x16x32 accumulator

__device__ __forceinline__ unsigned short f2bf(float f) {
  unsigned int u = __float_as_uint(f);
  u += 0x7fffu + ((u >> 16) & 1u);   // round-to-nearest-even
  return (unsigned short)(u >> 16);
}

__device__ __forceinline__ float tanh_fast(float x) {
  float e = __expf(2.0f * x);
  return 1.0f - 2.0f * __builtin_amdgcn_rcpf(e + 1.0f);
}

// ================= Round-9 prep: tiled LDS transpose repack =================
// Old prep mapped tid->OUTPUT element: W2 read one scalar f32/thread at 8KB
// stride = 16x overfetch, latency-bound => ~85us (25% of total, constant all
// rounds). New prep: each block owns a (kk, col-half) tile of W2 (32 rows x
// 1024 cols), reads it COALESCED (nt f4v), converts to bf16 into LDS, then
// each wave emits whole 1KB fragments with coalesced 16B stores.
//
// Fragment layouts (unchanged, consumed by pilayer_kernel):
// W1f idx = (((pass*4+kk)*8+ct)*64+lane)*8+j, val = W1[k*256 + n],
//     n = pass*128+ct*16+(lane&15), k = kk*32+(lane>>4)*8+j
// W2f idx = (((b*8+kk)*8+ct)*64+lane)*8+j,   val = W2[k*2048 + n*16+b],
//     n = ct*16+(lane&15),          k = kk*32+(lane>>4)*8+j
__global__ void __launch_bounds__(256)
prep2_kernel(const float* __restrict__ W1, const float* __restrict__ W2,
             unsigned short* __restrict__ W1f, unsigned short* __restrict__ W2f) {
  __shared__ unsigned short T[32 * 1024];   // 64 KB bf16 tile

  const int t = threadIdx.x;
  const int lane = t & 63;
  const int wv = t >> 6;
  const int l15 = lane & 15;
  const int l4 = lane >> 4;
  const int bid = blockIdx.x;

  if (bid < 16) {
    // ---- W2 tile: kk = bid>>1 (rows kk*32..+32), ch = bid&1 (cols ch*1024..+1024) ----
    const int kk = bid >> 1, ch = bid & 1;
    const float* src = W2 + (long)(kk * 32) * (N_IN * NB) + ch * 1024;
#pragma unroll
    for (int it = 0; it < 32; ++it) {
      int idx = it * 256 + t;          // 0..8191 float4-chunks
      int r = idx >> 8;                // 0..31
      int c4 = idx & 255;              // float4 within 1024 cols
      f4v v = __builtin_nontemporal_load((const f4v*)(src + r * (N_IN * NB) + c4 * 4));
      unsigned short* d = &T[r * 1024 + c4 * 4];
      d[0] = f2bf(v[0]); d[1] = f2bf(v[1]); d[2] = f2bf(v[2]); d[3] = f2bf(v[3]);
    }
    __syncthreads();
    // ---- emit 64 fragments (b:16 x ct_local:4), wave wv does fragments fi*4+wv ----
#pragma unroll
    for (int fi = 0; fi < 16; ++fi) {
      int f = fi * 4 + wv;             // 0..63
      int b = f >> 2, ctl = f & 3;
      int colb = ctl * 256 + l15 * 16 + b;   // local col = (ct*16+l15)*16+b - ch*1024
      s8v v;
#pragma unroll
      for (int j = 0; j < 8; ++j)
        v[j] = (short)T[(l4 * 8 + j) * 1024 + colb];
      *(s8v*)(W2f + ((((b * 8 + kk) * 8 + (ch * 4 + ctl)) * 64 + lane) << 3)) = v;
    }
  } else if (bid < 20) {
    // ---- W1 tile: kk = bid-16 (rows kk*32..+32), all 256 cols ----
    const int kk = bid - 16;
    const float* src = W1 + (long)(kk * 32) * HID;
#pragma unroll
    for (int it = 0; it < 8; ++it) {
      int idx = it * 256 + t;          // 0..2047 float4-chunks
      int r = idx >> 6;                // 0..31
      int c4 = idx & 63;               // float4 within 256 cols
      f4v v = __builtin_nontemporal_load((const f4v*)(src + r * HID + c4 * 4));
      unsigned short* d = &T[r * 256 + c4 * 4];
      d[0] = f2bf(v[0]); d[1] = f2bf(v[1]); d[2] = f2bf(v[2]); d[3] = f2bf(v[3]);
    }
    __syncthreads();
    // ---- emit 16 fragments (pass:2 x ct:8), wave wv does fragments fi*4+wv ----
#pragma unroll
    for (int fi = 0; fi < 4; ++fi) {
      int f = fi * 4 + wv;             // 0..15
      int pass = f >> 3, ct = f & 7;
      int col = pass * 128 + ct * 16 + l15;
      s8v v;
#pragma unroll
      for (int j = 0; j < 8; ++j)
        v[j] = (short)T[(l4 * 8 + j) * 256 + col];
      *(s8v*)(W1f + ((((pass * 4 + kk) * 8 + ct) * 64 + lane) << 3)) = v;
    }
  }
}

// ================= Proven round-1 fused kernel (253 us measured) =================
__global__ void __launch_bounds__(256, 2)
pilayer_kernel(const float* __restrict__ prop,
               const int* __restrict__ idx_i,
               const int* __restrict__ idx_j,
               const float* __restrict__ basis,
               const unsigned short* __restrict__ W1f,
               const unsigned short* __restrict__ W2f,
               float* __restrict__ out, int P) {
  __shared__ unsigned short Hs[BM * HS_STRIDE];   // 67,584 B (live through phase C)
  __shared__ float basisS[BM * BS_STRIDE];        //  8,704 B  -> 76.3 KB, 2 blocks/CU

  const int t = threadIdx.x;
  const int lane = t & 63;
  const int wv = t >> 6;
  const int l15 = lane & 15;
  const int l4 = lane >> 4;
  const int tile0 = blockIdx.x * BM;
  const int row0 = wv * 32;

  // ---- edge indices at kernel top: head of the idx->prop pointer-chase ----
  int pidx[2], qidx[2];
#pragma unroll
  for (int rt = 0; rt < 2; ++rt) {
    int p = tile0 + row0 + rt * 16 + l15; if (p >= P) p = P - 1;
    pidx[rt] = idx_i[p];
    qidx[rt] = idx_j[p];
  }

  // ---- stage basis tile cooperatively (nt loads: basis streamed exactly once) ----
  {
    int r = t >> 1;
    int c0 = (t & 1) * 8;
    int p = tile0 + r; if (p >= P) p = P - 1;
    const f4v* bp = (const f4v*)(basis + (long)p * NB + c0);
    f4v b0 = __builtin_nontemporal_load(bp);
    f4v b1 = __builtin_nontemporal_load(bp + 1);
    float* dst = &basisS[r * BS_STRIDE + c0];
    dst[0] = b0[0]; dst[1] = b0[1]; dst[2] = b0[2]; dst[3] = b0[3];
    dst[4] = b1[0]; dst[5] = b1[1]; dst[6] = b1[2]; dst[7] = b1[3];
  }

  // ---- Phase B: wave wv computes H rows [32*wv, 32*wv+32), all 256 cols ----
  {
    s8v afr[4][2];   // [kk][rt], 32 VGPR; gathers issued once, reused by both passes
#pragma unroll
    for (int kk = 0; kk < 4; ++kk) {
      int k0 = kk * 32 + l4 * 8;
#pragma unroll
      for (int rt = 0; rt < 2; ++rt) {
        const float4* ai = (const float4*)(prop + (long)pidx[rt] * N_IN + k0);
        const float4* aj = (const float4*)(prop + (long)qidx[rt] * N_IN + k0);
        float4 x0 = ai[0], x1 = ai[1];
        float4 y0 = aj[0], y1 = aj[1];
        s8v a;
        a[0] = (short)f2bf(x0.x + y0.x); a[1] = (short)f2bf(x0.y + y0.y);
        a[2] = (short)f2bf(x0.z + y0.z); a[3] = (short)f2bf(x0.w + y0.w);
        a[4] = (short)f2bf(x1.x + y1.x); a[5] = (short)f2bf(x1.y + y1.y);
        a[6] = (short)f2bf(x1.z + y1.z); a[7] = (short)f2bf(x1.w + y1.w);
        afr[kk][rt] = a;
      }
    }
#pragma unroll
    for (int pass = 0; pass < 2; ++pass) {
      f4v acc[2][8];
#pragma unroll
      for (int rt = 0; rt < 2; ++rt)
#pragma unroll
        for (int ct = 0; ct < 8; ++ct) acc[rt][ct] = (f4v){0.f, 0.f, 0.f, 0.f};
#pragma unroll
      for (int kk = 0; kk < 4; ++kk) {
#pragma unroll
        for (int ct = 0; ct < 8; ++ct) {
          s8v bfr = *(const s8v*)(W1f + ((((pass * 4 + kk) * 8 + ct) * 64 + lane) << 3));
#pragma unroll
          for (int rt = 0; rt < 2; ++rt)
            acc[rt][ct] = __builtin_amdgcn_mfma_f32_16x16x32_bf16(afr[kk][rt], bfr, acc[rt][ct], 0, 0, 0);
        }
      }
#pragma unroll
      for (int rt = 0; rt < 2; ++rt)
#pragma unroll
        for (int ct = 0; ct < 8; ++ct)
#pragma unroll
          for (int r = 0; r < 4; ++r) {
            int lrow = row0 + rt * 16 + l4 * 4 + r;
            int col = pass * 128 + ct * 16 + l15;
            Hs[lrow * HS_STRIDE + col] = f2bf(tanh_fast(acc[rt][ct][r]));
          }
    }
  }

  __syncthreads();   // H + basis visible to all waves

  // ---- Phase C: 2x2 wave partition; wave (rg,cg) owns rows rg*64..+64, cols cg*64..+64.
  // A (H) cached in registers per K-half; B prefetched from W2f at distance 3. ----
  const int rg = wv >> 1, cg = wv & 1;
  const int rbase = rg * 64;

  f4v o[4][4];   // [rt][q] -> rows rbase+rt*16.., cols (cg*4+q)*16..
#pragma unroll
  for (int rt = 0; rt < 4; ++rt)
#pragma unroll
    for (int q = 0; q < 4; ++q) o[rt][q] = (f4v){0.f, 0.f, 0.f, 0.f};

#pragma unroll 1
  for (int khalf = 0; khalf < 2; ++khalf) {
    // A-cache: 16 fragments (64 VGPR), reused across all 16 b and 4 q
    s8v areg[4][4];   // [rt][kloc]
#pragma unroll
    for (int rt = 0; rt < 4; ++rt)
#pragma unroll
      for (int kloc = 0; kloc < 4; ++kloc)
        areg[rt][kloc] = *(const s8v*)&Hs[(rbase + rt * 16 + l15) * HS_STRIDE +
                                          (khalf * 4 + kloc) * 32 + l4 * 8];

    s8v bf[4][4];   // register ring of B fragments [slot][kloc], slot = it & 3
    // preload iterations 0,1,2  (b=0, q=0..2)
#pragma unroll
    for (int q0 = 0; q0 < 3; ++q0)
#pragma unroll
      for (int kloc = 0; kloc < 4; ++kloc)
        bf[q0][kloc] = *(const s8v*)(W2f +
            ((((khalf * 4 + kloc) * 8) + cg * 4 + q0) << 9) + lane * 8);

#pragma unroll 1
    for (int b = 0; b < 16; ++b) {
      float bs[4][4];
#pragma unroll
      for (int rt = 0; rt < 4; ++rt)
#pragma unroll
        for (int r = 0; r < 4; ++r)
          bs[rt][r] = basisS[(rbase + rt * 16 + l4 * 4 + r) * BS_STRIDE + b];

#pragma unroll
      for (int q = 0; q < 4; ++q) {
        // prefetch iteration it+3 into slot (q+3)&3  (it = b*4+q)
        {
          int nb = b + ((q + 3) >> 2); if (nb > 15) nb = 15;   // tail: harmless re-read
          int nq = (q + 3) & 3;
#pragma unroll
          for (int kloc = 0; kloc < 4; ++kloc)
            bf[(q + 3) & 3][kloc] = *(const s8v*)(W2f +
                (((nb * 8 + khalf * 4 + kloc) * 8 + cg * 4 + nq) << 9) + lane * 8);
        }
        f4v g[4];
#pragma unroll
        for (int rt = 0; rt < 4; ++rt) g[rt] = (f4v){0.f, 0.f, 0.f, 0.f};
        __builtin_amdgcn_s_setprio(1);   // T5: barrier-free independent waves in b-loop
#pragma unroll
        for (int kloc = 0; kloc < 4; ++kloc)
#pragma unroll
          for (int rt = 0; rt < 4; ++rt)
            g[rt] = __builtin_amdgcn_mfma_f32_16x16x32_bf16(areg[rt][kloc], bf[q][kloc], g[rt], 0, 0, 0);
        __builtin_amdgcn_s_setprio(0);
#pragma unroll
        for (int rt = 0; rt < 4; ++rt)
#pragma unroll
          for (int r = 0; r < 4; ++r)
            o[rt][q][r] += g[rt][r] * bs[rt][r];
      }
    }
  }

  // ---- epilogue: out[p][c], c = (cg*4+q)*16 + l15. Non-temporal: out is
  // write-once/never-read -> keep it from evicting W2f out of L2. ----
#pragma unroll
  for (int rt = 0; rt < 4; ++rt)
#pragma unroll
    for (int r = 0; r < 4; ++r) {
      int p = tile0 + rbase + rt * 16 + l4 * 4 + r;
      if (p < P) {
        float* op = out + (long)p * N_IN + cg * 64 + l15;
#pragma unroll
        for (int q = 0; q < 4; ++q)
          __builtin_nontemporal_store(o[rt][q][r], op + q * 16);
      }
    }
}

extern "C" void kernel_launch(void* const* d_in, const int* in_sizes, int n_in,
                              void* d_out, int out_size, void* d_ws, size_t ws_size,
                              hipStream_t stream) {
  const float* prop  = (const float*)d_in[0];
  const int* idx_i   = (const int*)d_in[1];
  const int* idx_j   = (const int*)d_in[2];
  const float* basis = (const float*)d_in[3];
  const float* W1    = (const float*)d_in[4];
  const float* W2    = (const float*)d_in[5];
  float* out = (float*)d_out;
  int P = in_sizes[1];

  unsigned short* W1f = (unsigned short*)d_ws;                 // 32768 bf16
  unsigned short* W2f = W1f + N_IN * HID;                      // 524288 bf16

  prep2_kernel<<<20, 256, 0, stream>>>(W1, W2, W1f, W2f);

  int ntiles = (P + BM - 1) / BM;
  pilayer_kernel<<<ntiles, 256, 0, stream>>>(prop, idx_i, idx_j, basis, W1f, W2f, out, P);
}

// Round 10
// 332.961 us; speedup vs baseline: 1.1103x; 1.0108x over previous
//
#include <hip/hip_runtime.h>

#define N_IN 128
#define HID 256
#define NB 16
#define BM 128
#define HS_STRIDE 264   // bf16 row stride for H tile (16B pad -> 2-way banks only, free)
#define BS_STRIDE 17    // basis LDS stride (f32)

typedef __attribute__((ext_vector_type(8))) short s8v;   // 8 bf16 = 4 VGPRs
typedef __attribute__((ext_vector_type(4))) float f4v;   // MFMA 16x16x32 accumulator

__device__ __forceinline__ unsigned short f2bf(float f) {
  unsigned int u = __float_as_uint(f);
  u += 0x7fffu + ((u >> 16) & 1u);   // round-to-nearest-even
  return (unsigned short)(u >> 16);
}

__device__ __forceinline__ float tanh_fast(float x) {
  float e = __expf(2.0f * x);
  return 1.0f - 2.0f * __builtin_amdgcn_rcpf(e + 1.0f);
}

// ================= Round-10 prep: 68-block tiled repack =================
// Round-9's 20-block prep left 236/256 CUs idle for its whole duration (grid
// bubble) and each block carried 4x the emit work. Re-tile to 32x256 tiles
// (16 KB LDS): W2 = 64 blocks (kk 0..7 x ctile 0..7), W1 = 4 blocks. Fragment
// math identical to the round-9 HW-validated kernel (W1 branch verbatim; W2
// branch same modulo tile index). pilayer untouched -> clean A/B on the
// "total - pilayer" gap: drop => prep was the cost; flat => harness overhead.
//
// Fragment layouts (consumed by pilayer_kernel):
// W1f idx = (((pass*4+kk)*8+ct)*64+lane)*8+j, val = W1[k*256 + n],
//     n = pass*128+ct*16+(lane&15), k = kk*32+(lane>>4)*8+j
// W2f idx = (((b*8+kk)*8+ct)*64+lane)*8+j,   val = W2[k*2048 + n*16+b],
//     n = ct*16+(lane&15),          k = kk*32+(lane>>4)*8+j
__global__ void __launch_bounds__(256)
prep3_kernel(const float* __restrict__ W1, const float* __restrict__ W2,
             unsigned short* __restrict__ W1f, unsigned short* __restrict__ W2f) {
  __shared__ unsigned short T[32 * 256];   // 16 KB bf16 tile

  const int t = threadIdx.x;
  const int lane = t & 63;
  const int wv = t >> 6;
  const int l15 = lane & 15;
  const int l4 = lane >> 4;
  const int bid = blockIdx.x;

  const bool isW2 = bid < 64;
  // W2: kk = bid>>3 (K-rows kk*32..+32 of 256), ctile = bid&7 (cols ctile*256..+256)
  // W1: kk = bid-64 (K-rows kk*32..+32 of 128), all 256 cols
  const int kk = isW2 ? (bid >> 3) : (bid - 64);
  const int ctile = isW2 ? (bid & 7) : 0;
  const float* src = isW2 ? (W2 + (long)(kk * 32) * (N_IN * NB) + ctile * 256)
                          : (W1 + (long)(kk * 32) * HID);
  const int srcStride = isW2 ? (N_IN * NB) : HID;

  // ---- load 32x256 f32 tile, coalesced nt f4v (read-once) ----
#pragma unroll
  for (int it = 0; it < 8; ++it) {
    int idx = it * 256 + t;          // 0..2047 f4-chunks
    int r = idx >> 6;                // 0..31
    int c4 = idx & 63;               // f4 within 256 cols
    f4v v = __builtin_nontemporal_load((const f4v*)(src + r * srcStride + c4 * 4));
    unsigned short* d = &T[r * 256 + c4 * 4];
    d[0] = f2bf(v[0]); d[1] = f2bf(v[1]); d[2] = f2bf(v[2]); d[3] = f2bf(v[3]);
  }
  __syncthreads();

  // ---- emit 16 fragments (wave wv does f = fi*4+wv), coalesced 16B stores ----
#pragma unroll
  for (int fi = 0; fi < 4; ++fi) {
    int f = fi * 4 + wv;             // 0..15
    s8v v;
    if (isW2) {
      int b = f;                     // one fragment per basis index b
      int colb = l15 * 16 + b;       // local col within the 256-col tile
#pragma unroll
      for (int j = 0; j < 8; ++j)
        v[j] = (short)T[(l4 * 8 + j) * 256 + colb];
      *(s8v*)(W2f + ((((b * 8 + kk) * 8 + ctile) * 64 + lane) << 3)) = v;
    } else {
      int pass = f >> 3, ct = f & 7;
      int col = pass * 128 + ct * 16 + l15;
#pragma unroll
      for (int j = 0; j < 8; ++j)
        v[j] = (short)T[(l4 * 8 + j) * 256 + col];
      *(s8v*)(W1f + ((((pass * 4 + kk) * 8 + ct) * 64 + lane) << 3)) = v;
    }
  }
}

// ================= Proven fused kernel (236-253 us measured; UNCHANGED) =================
__global__ void __launch_bounds__(256, 2)
pilayer_kernel(const float* __restrict__ prop,
               const int* __restrict__ idx_i,
               const int* __restrict__ idx_j,
               const float* __restrict__ basis,
               const unsigned short* __restrict__ W1f,
               const unsigned short* __restrict__ W2f,
               float* __restrict__ out, int P) {
  __shared__ unsigned short Hs[BM * HS_STRIDE];   // 67,584 B (live through phase C)
  __shared__ float basisS[BM * BS_STRIDE];        //  8,704 B  -> 76.3 KB, 2 blocks/CU

  const int t = threadIdx.x;
  const int lane = t & 63;
  const int wv = t >> 6;
  const int l15 = lane & 15;
  const int l4 = lane >> 4;
  const int tile0 = blockIdx.x * BM;
  const int row0 = wv * 32;

  // ---- edge indices at kernel top: head of the idx->prop pointer-chase ----
  int pidx[2], qidx[2];
#pragma unroll
  for (int rt = 0; rt < 2; ++rt) {
    int p = tile0 + row0 + rt * 16 + l15; if (p >= P) p = P - 1;
    pidx[rt] = idx_i[p];
    qidx[rt] = idx_j[p];
  }

  // ---- stage basis tile cooperatively (nt loads: basis streamed exactly once) ----
  {
    int r = t >> 1;
    int c0 = (t & 1) * 8;
    int p = tile0 + r; if (p >= P) p = P - 1;
    const f4v* bp = (const f4v*)(basis + (long)p * NB + c0);
    f4v b0 = __builtin_nontemporal_load(bp);
    f4v b1 = __builtin_nontemporal_load(bp + 1);
    float* dst = &basisS[r * BS_STRIDE + c0];
    dst[0] = b0[0]; dst[1] = b0[1]; dst[2] = b0[2]; dst[3] = b0[3];
    dst[4] = b1[0]; dst[5] = b1[1]; dst[6] = b1[2]; dst[7] = b1[3];
  }

  // ---- Phase B: wave wv computes H rows [32*wv, 32*wv+32), all 256 cols ----
  {
    s8v afr[4][2];   // [kk][rt], 32 VGPR; gathers issued once, reused by both passes
#pragma unroll
    for (int kk = 0; kk < 4; ++kk) {
      int k0 = kk * 32 + l4 * 8;
#pragma unroll
      for (int rt = 0; rt < 2; ++rt) {
        const float4* ai = (const float4*)(prop + (long)pidx[rt] * N_IN + k0);
        const float4* aj = (const float4*)(prop + (long)qidx[rt] * N_IN + k0);
        float4 x0 = ai[0], x1 = ai[1];
        float4 y0 = aj[0], y1 = aj[1];
        s8v a;
        a[0] = (short)f2bf(x0.x + y0.x); a[1] = (short)f2bf(x0.y + y0.y);
        a[2] = (short)f2bf(x0.z + y0.z); a[3] = (short)f2bf(x0.w + y0.w);
        a[4] = (short)f2bf(x1.x + y1.x); a[5] = (short)f2bf(x1.y + y1.y);
        a[6] = (short)f2bf(x1.z + y1.z); a[7] = (short)f2bf(x1.w + y1.w);
        afr[kk][rt] = a;
      }
    }
#pragma unroll
    for (int pass = 0; pass < 2; ++pass) {
      f4v acc[2][8];
#pragma unroll
      for (int rt = 0; rt < 2; ++rt)
#pragma unroll
        for (int ct = 0; ct < 8; ++ct) acc[rt][ct] = (f4v){0.f, 0.f, 0.f, 0.f};
#pragma unroll
      for (int kk = 0; kk < 4; ++kk) {
#pragma unroll
        for (int ct = 0; ct < 8; ++ct) {
          s8v bfr = *(const s8v*)(W1f + ((((pass * 4 + kk) * 8 + ct) * 64 + lane) << 3));
#pragma unroll
          for (int rt = 0; rt < 2; ++rt)
            acc[rt][ct] = __builtin_amdgcn_mfma_f32_16x16x32_bf16(afr[kk][rt], bfr, acc[rt][ct], 0, 0, 0);
        }
      }
#pragma unroll
      for (int rt = 0; rt < 2; ++rt)
#pragma unroll
        for (int ct = 0; ct < 8; ++ct)
#pragma unroll
          for (int r = 0; r < 4; ++r) {
            int lrow = row0 + rt * 16 + l4 * 4 + r;
            int col = pass * 128 + ct * 16 + l15;
            Hs[lrow * HS_STRIDE + col] = f2bf(tanh_fast(acc[rt][ct][r]));
          }
    }
  }

  __syncthreads();   // H + basis visible to all waves

  // ---- Phase C: 2x2 wave partition; wave (rg,cg) owns rows rg*64..+64, cols cg*64..+64.
  // A (H) cached in registers per K-half; B prefetched from W2f at distance 3. ----
  const int rg = wv >> 1, cg = wv & 1;
  const int rbase = rg * 64;

  f4v o[4][4];   // [rt][q] -> rows rbase+rt*16.., cols (cg*4+q)*16..
#pragma unroll
  for (int rt = 0; rt < 4; ++rt)
#pragma unroll
    for (int q = 0; q < 4; ++q) o[rt][q] = (f4v){0.f, 0.f, 0.f, 0.f};

#pragma unroll 1
  for (int khalf = 0; khalf < 2; ++khalf) {
    // A-cache: 16 fragments (64 VGPR), reused across all 16 b and 4 q
    s8v areg[4][4];   // [rt][kloc]
#pragma unroll
    for (int rt = 0; rt < 4; ++rt)
#pragma unroll
      for (int kloc = 0; kloc < 4; ++kloc)
        areg[rt][kloc] = *(const s8v*)&Hs[(rbase + rt * 16 + l15) * HS_STRIDE +
                                          (khalf * 4 + kloc) * 32 + l4 * 8];

    s8v bf[4][4];   // register ring of B fragments [slot][kloc], slot = it & 3
    // preload iterations 0,1,2  (b=0, q=0..2)
#pragma unroll
    for (int q0 = 0; q0 < 3; ++q0)
#pragma unroll
      for (int kloc = 0; kloc < 4; ++kloc)
        bf[q0][kloc] = *(const s8v*)(W2f +
            ((((khalf * 4 + kloc) * 8) + cg * 4 + q0) << 9) + lane * 8);

#pragma unroll 1
    for (int b = 0; b < 16; ++b) {
      float bs[4][4];
#pragma unroll
      for (int rt = 0; rt < 4; ++rt)
#pragma unroll
        for (int r = 0; r < 4; ++r)
          bs[rt][r] = basisS[(rbase + rt * 16 + l4 * 4 + r) * BS_STRIDE + b];

#pragma unroll
      for (int q = 0; q < 4; ++q) {
        // prefetch iteration it+3 into slot (q+3)&3  (it = b*4+q)
        {
          int nb = b + ((q + 3) >> 2); if (nb > 15) nb = 15;   // tail: harmless re-read
          int nq = (q + 3) & 3;
#pragma unroll
          for (int kloc = 0; kloc < 4; ++kloc)
            bf[(q + 3) & 3][kloc] = *(const s8v*)(W2f +
                (((nb * 8 + khalf * 4 + kloc) * 8 + cg * 4 + nq) << 9) + lane * 8);
        }
        f4v g[4];
#pragma unroll
        for (int rt = 0; rt < 4; ++rt) g[rt] = (f4v){0.f, 0.f, 0.f, 0.f};
        __builtin_amdgcn_s_setprio(1);   // T5: barrier-free independent waves in b-loop
#pragma unroll
        for (int kloc = 0; kloc < 4; ++kloc)
#pragma unroll
          for (int rt = 0; rt < 4; ++rt)
            g[rt] = __builtin_amdgcn_mfma_f32_16x16x32_bf16(areg[rt][kloc], bf[q][kloc], g[rt], 0, 0, 0);
        __builtin_amdgcn_s_setprio(0);
#pragma unroll
        for (int rt = 0; rt < 4; ++rt)
#pragma unroll
          for (int r = 0; r < 4; ++r)
            o[rt][q][r] += g[rt][r] * bs[rt][r];
      }
    }
  }

  // ---- epilogue: out[p][c], c = (cg*4+q)*16 + l15. Non-temporal: out is
  // write-once/never-read -> keep it from evicting W2f out of L2. ----
#pragma unroll
  for (int rt = 0; rt < 4; ++rt)
#pragma unroll
    for (int r = 0; r < 4; ++r) {
      int p = tile0 + rbase + rt * 16 + l4 * 4 + r;
      if (p < P) {
        float* op = out + (long)p * N_IN + cg * 64 + l15;
#pragma unroll
        for (int q = 0; q < 4; ++q)
          __builtin_nontemporal_store(o[rt][q][r], op + q * 16);
      }
    }
}

extern "C" void kernel_launch(void* const* d_in, const int* in_sizes, int n_in,
                              void* d_out, int out_size, void* d_ws, size_t ws_size,
                              hipStream_t stream) {
  const float* prop  = (const float*)d_in[0];
  const int* idx_i   = (const int*)d_in[1];
  const int* idx_j   = (const int*)d_in[2];
  const float* basis = (const float*)d_in[3];
  const float* W1    = (const float*)d_in[4];
  const float* W2    = (const float*)d_in[5];
  float* out = (float*)d_out;
  int P = in_sizes[1];

  unsigned short* W1f = (unsigned short*)d_ws;                 // 32768 bf16
  unsigned short* W2f = W1f + N_IN * HID;                      // 524288 bf16

  prep3_kernel<<<68, 256, 0, stream>>>(W1, W2, W1f, W2f);

  int ntiles = (P + BM - 1) / BM;
  pilayer_kernel<<<ntiles, 256, 0, stream>>>(prop, idx_i, idx_j, basis, W1f, W2f, out, P);
}